// Round 1
// baseline (2391.845 us; speedup 1.0000x reference)
//
#include <hip/hip_runtime.h>
#include <math.h>

#define EMB 128

// ---------------- helpers ----------------

// inclusive Hillis-Steele scan over a 256-thread block (int)
__device__ __forceinline__ int incl_scan_256(int v, int* lds) {
    int tid = threadIdx.x;
    lds[tid] = v;
    __syncthreads();
    #pragma unroll
    for (int off = 1; off < 256; off <<= 1) {
        int t = (tid >= off) ? lds[tid - off] : 0;
        __syncthreads();
        lds[tid] += t;
        __syncthreads();
    }
    return lds[tid];
}

#define F4E(v, j) ((j) == 0 ? (v).x : ((j) == 1 ? (v).y : ((j) == 2 ? (v).z : (v).w)))

// ---------------- generic [M,128] @ [128,128] projection ----------------
// Y[r, :] = act( X[r,:] @ W + bias + C[r,:] )
// block = 256 (4 waves); each wave: 64 lanes x 2 cols, 4 rows at a time, 16 rows/wave
// W staged in LDS (64 KB). Register blocking 4 rows x 2 cols amortizes LDS reads.
__global__ __launch_bounds__(256) void proj_kernel(
    const float* __restrict__ X, const float* __restrict__ W,
    const float* __restrict__ bias, const float* __restrict__ C,
    float* __restrict__ Y, int M, int relu)
{
    __shared__ float Wl[EMB * EMB];
    const int tid = threadIdx.x;
    for (int i = tid; i < EMB * EMB / 4; i += 256)
        ((float4*)Wl)[i] = ((const float4*)W)[i];
    __syncthreads();

    const int wave = tid >> 6, lane = tid & 63;
    const int base = blockIdx.x * 64 + wave * 16;

    float2 bv = make_float2(0.f, 0.f);
    if (bias) bv = *(const float2*)(bias + 2 * lane);

    for (int g = 0; g < 4; ++g) {
        const int r0 = base + g * 4;
        int rc[4];
        #pragma unroll
        for (int j = 0; j < 4; ++j) { int r = r0 + j; rc[j] = (r < M) ? r : (M - 1); }
        const float4* p0 = (const float4*)(X + (size_t)rc[0] * EMB);
        const float4* p1 = (const float4*)(X + (size_t)rc[1] * EMB);
        const float4* p2 = (const float4*)(X + (size_t)rc[2] * EMB);
        const float4* p3 = (const float4*)(X + (size_t)rc[3] * EMB);
        float2 a0 = bv, a1 = bv, a2 = bv, a3 = bv;
        #pragma unroll 4
        for (int k4 = 0; k4 < 32; ++k4) {
            float4 x0 = p0[k4], x1 = p1[k4], x2 = p2[k4], x3 = p3[k4];
            #pragma unroll
            for (int j = 0; j < 4; ++j) {
                float2 w = ((const float2*)(Wl + (k4 * 4 + j) * EMB))[lane];
                float f0 = F4E(x0, j), f1 = F4E(x1, j), f2 = F4E(x2, j), f3 = F4E(x3, j);
                a0.x += f0 * w.x; a0.y += f0 * w.y;
                a1.x += f1 * w.x; a1.y += f1 * w.y;
                a2.x += f2 * w.x; a2.y += f2 * w.y;
                a3.x += f3 * w.x; a3.y += f3 * w.y;
            }
        }
        #pragma unroll
        for (int j = 0; j < 4; ++j) {
            if (r0 + j < M) {
                float2 a = (j == 0) ? a0 : ((j == 1) ? a1 : ((j == 2) ? a2 : a3));
                if (C) {
                    float2 c = *(const float2*)(C + (size_t)(r0 + j) * EMB + 2 * lane);
                    a.x += c.x; a.y += c.y;
                }
                if (relu) { a.x = fmaxf(a.x, 0.f); a.y = fmaxf(a.y, 0.f); }
                *(float2*)(Y + (size_t)(r0 + j) * EMB + 2 * lane) = a;
            }
        }
    }
}

// ---------------- fused edge kernel ----------------
// per edge: e = ef @ W_e (no bias); z = leaky(x_l[src]+x_r[dst]+e, 0.2);
// logit[h] = sum_o z[h,o]*att[h,o]; ex[e,h] = exp(logit)   (no max-sub; logits ~ O(1))
__global__ __launch_bounds__(256) void edge_kernel(
    const float* __restrict__ EF, const float* __restrict__ We,
    const float* __restrict__ xl, const float* __restrict__ xr,
    const int* __restrict__ src, const int* __restrict__ dst,
    const float* __restrict__ att, float* __restrict__ exb, int En)
{
    __shared__ float Wl[EMB * EMB];
    const int tid = threadIdx.x;
    for (int i = tid; i < EMB * EMB / 4; i += 256)
        ((float4*)Wl)[i] = ((const float4*)We)[i];
    __syncthreads();

    const int wave = tid >> 6, lane = tid & 63;
    const float att0 = att[2 * lane], att1 = att[2 * lane + 1];
    const int head = lane >> 4;  // lanes 0-15 cols 0-31 = head0, etc.
    const int base = blockIdx.x * 64 + wave * 16;

    for (int g = 0; g < 4; ++g) {
        const int e0 = base + g * 4;
        int ec[4];
        #pragma unroll
        for (int j = 0; j < 4; ++j) { int e = e0 + j; ec[j] = (e < En) ? e : (En - 1); }
        const float4* p0 = (const float4*)(EF + (size_t)ec[0] * EMB);
        const float4* p1 = (const float4*)(EF + (size_t)ec[1] * EMB);
        const float4* p2 = (const float4*)(EF + (size_t)ec[2] * EMB);
        const float4* p3 = (const float4*)(EF + (size_t)ec[3] * EMB);
        float2 a0 = {0.f, 0.f}, a1 = {0.f, 0.f}, a2 = {0.f, 0.f}, a3 = {0.f, 0.f};
        #pragma unroll 4
        for (int k4 = 0; k4 < 32; ++k4) {
            float4 x0 = p0[k4], x1 = p1[k4], x2 = p2[k4], x3 = p3[k4];
            #pragma unroll
            for (int j = 0; j < 4; ++j) {
                float2 w = ((const float2*)(Wl + (k4 * 4 + j) * EMB))[lane];
                float f0 = F4E(x0, j), f1 = F4E(x1, j), f2 = F4E(x2, j), f3 = F4E(x3, j);
                a0.x += f0 * w.x; a0.y += f0 * w.y;
                a1.x += f1 * w.x; a1.y += f1 * w.y;
                a2.x += f2 * w.x; a2.y += f2 * w.y;
                a3.x += f3 * w.x; a3.y += f3 * w.y;
            }
        }
        #pragma unroll
        for (int j = 0; j < 4; ++j) {
            const int e = ec[j];
            const int s = src[e], d = dst[e];
            float2 xlv = ((const float2*)(xl + (size_t)s * EMB))[lane];
            float2 xrv = ((const float2*)(xr + (size_t)d * EMB))[lane];
            float2 a = (j == 0) ? a0 : ((j == 1) ? a1 : ((j == 2) ? a2 : a3));
            float z0 = a.x + xlv.x + xrv.x; z0 = (z0 > 0.f) ? z0 : 0.2f * z0;
            float z1 = a.y + xlv.y + xrv.y; z1 = (z1 > 0.f) ? z1 : 0.2f * z1;
            float part = z0 * att0 + z1 * att1;
            // reduce over the 16-lane head group (32 cols)
            part += __shfl_xor(part, 1);
            part += __shfl_xor(part, 2);
            part += __shfl_xor(part, 4);
            part += __shfl_xor(part, 8);
            if ((lane & 15) == 0 && (e0 + j) < En)
                exb[(size_t)e * 4 + head] = expf(part);
        }
    }
}

// ---------------- CSR build ----------------
__global__ void hist_kernel(const int* __restrict__ dst, int* __restrict__ counts, int En) {
    int i = blockIdx.x * 256 + threadIdx.x;
    if (i < En) atomicAdd(&counts[dst[i]], 1);
}

__global__ void scan1_kernel(const int* __restrict__ counts, int* __restrict__ bsum, int N) {
    __shared__ int red[4];
    int i = blockIdx.x * 256 + threadIdx.x;
    int v = (i < N) ? counts[i] : 0;
    #pragma unroll
    for (int m = 1; m < 64; m <<= 1) v += __shfl_xor(v, m);
    if ((threadIdx.x & 63) == 0) red[threadIdx.x >> 6] = v;
    __syncthreads();
    if (threadIdx.x == 0) bsum[blockIdx.x] = red[0] + red[1] + red[2] + red[3];
}

__global__ void scan2_kernel(int* __restrict__ bsum, int* __restrict__ boff, int nb,
                             int* __restrict__ offs, int NRtot, int Etot) {
    __shared__ int lds[256];
    int tid = threadIdx.x;
    int v = (tid < nb) ? bsum[tid] : 0;
    int incl = incl_scan_256(v, lds);
    if (tid < nb) boff[tid] = incl - v;
    if (tid == 0) offs[NRtot] = Etot;
}

__global__ void scan3_kernel(const int* __restrict__ counts, const int* __restrict__ boff,
                             int* __restrict__ offs, int* __restrict__ cursor, int N) {
    __shared__ int lds[256];
    int tid = threadIdx.x;
    int i = blockIdx.x * 256 + tid;
    int v = (i < N) ? counts[i] : 0;
    int incl = incl_scan_256(v, lds);
    int excl = incl - v + boff[blockIdx.x];
    if (i < N) { offs[i] = excl; cursor[i] = excl; }
}

__global__ void scatter_kernel(const int* __restrict__ dst, int* __restrict__ cursor,
                               int* __restrict__ csr, int En) {
    int i = blockIdx.x * 256 + threadIdx.x;
    if (i < En) { int p = atomicAdd(&cursor[dst[i]], 1); csr[p] = i; }
}

// ---------------- message accumulation + softmax-normalize + LayerNorm ----------------
// one block (128 thr) per dst node; den computed locally (no atomics).
// msg = (sum_e ex_e * x_l[src_e]) / (den + 1e-16) + b_conv, then LN over 128 dims.
__global__ __launch_bounds__(128) void msg_ln_kernel(
    const float* __restrict__ xl, const float* __restrict__ exb,
    const int* __restrict__ csr, const int* __restrict__ offs,
    const int* __restrict__ src, const float* __restrict__ bconv,
    const float* __restrict__ ln_g, const float* __restrict__ ln_b,
    float* __restrict__ msg)
{
    const int d = blockIdx.x;
    const int tid = threadIdx.x;
    const int h = tid >> 5;
    const int beg = offs[d], end = offs[d + 1];
    float acc = 0.f, den = 0.f;
    for (int i = beg; i < end; ++i) {
        int e = csr[i];
        float exv = exb[(size_t)e * 4 + h];
        int s = src[e];
        acc += exv * xl[(size_t)s * EMB + tid];
        den += exv;
    }
    float m = acc / (den + 1e-16f) + bconv[tid];

    __shared__ float red[2];
    float s1 = m;
    #pragma unroll
    for (int mk = 1; mk < 64; mk <<= 1) s1 += __shfl_xor(s1, mk);
    if ((tid & 63) == 0) red[tid >> 6] = s1;
    __syncthreads();
    float mu = (red[0] + red[1]) * (1.f / EMB);
    __syncthreads();
    float c = m - mu;
    float s2 = c * c;
    #pragma unroll
    for (int mk = 1; mk < 64; mk <<= 1) s2 += __shfl_xor(s2, mk);
    if ((tid & 63) == 0) red[tid >> 6] = s2;
    __syncthreads();
    float var = (red[0] + red[1]) * (1.f / EMB);
    float y = c * (1.f / sqrtf(var + 1e-5f)) * ln_g[tid] + ln_b[tid];
    msg[(size_t)d * EMB + tid] = y;
}

// ---------------- launch ----------------
extern "C" void kernel_launch(void* const* d_in, const int* in_sizes, int n_in,
                              void* d_out, int out_size, void* d_ws, size_t ws_size,
                              hipStream_t stream) {
    const float* left  = (const float*)d_in[0];
    const int*   eidx  = (const int*)d_in[1];
    const float* ef    = (const float*)d_in[2];
    const float* right = (const float*)d_in[3];
    const float* W_l   = (const float*)d_in[4];
    const float* b_l   = (const float*)d_in[5];
    const float* W_r   = (const float*)d_in[6];
    const float* b_r   = (const float*)d_in[7];
    const float* W_e   = (const float*)d_in[8];
    const float* att   = (const float*)d_in[9];
    const float* bconv = (const float*)d_in[10];
    const float* ln_g  = (const float*)d_in[11];
    const float* ln_b  = (const float*)d_in[12];
    const float* W1    = (const float*)d_in[13];
    const float* b1    = (const float*)d_in[14];
    const float* W2    = (const float*)d_in[15];
    const float* b2    = (const float*)d_in[16];

    const int NLn = in_sizes[0] / EMB;
    const int En  = in_sizes[1] / 2;
    const int NRn = in_sizes[3] / EMB;
    const int* src  = eidx;
    const int* dstp = eidx + En;

    // workspace carve
    float* fws = (float*)d_ws;
    size_t off = 0;
    float* x_l = fws + off; off += (size_t)NLn * EMB;
    float* x_r = fws + off; off += (size_t)NRn * EMB;   // later reused as MLP partial buf
    float* exb = fws + off; off += (size_t)En * 4;
    float* msg = fws + off; off += (size_t)NRn * EMB;   // later reused as h buf
    int* counts = (int*)(fws + off);
    int* offs   = counts + NRn;
    int* cursor = offs + NRn + 1;
    int* bsum   = cursor + NRn;
    int* boff   = bsum + 256;
    int* csr    = boff + 256;

    const int nb = (NRn + 255) / 256;
    const int gP_L = (NLn + 63) / 64;
    const int gP_R = (NRn + 63) / 64;
    const int gE64 = (En + 63) / 64;
    const int gE256 = (En + 255) / 256;

    hipMemsetAsync(counts, 0, (size_t)NRn * sizeof(int), stream);

    // node projections
    proj_kernel<<<gP_L, 256, 0, stream>>>(left,  W_l, b_l, nullptr, x_l, NLn, 0);
    proj_kernel<<<gP_R, 256, 0, stream>>>(right, W_r, b_r, nullptr, x_r, NRn, 0);

    // CSR by dst
    hist_kernel<<<gE256, 256, 0, stream>>>(dstp, counts, En);
    scan1_kernel<<<nb, 256, 0, stream>>>(counts, bsum, NRn);
    scan2_kernel<<<1, 256, 0, stream>>>(bsum, boff, nb, offs, NRn, En);
    scan3_kernel<<<nb, 256, 0, stream>>>(counts, boff, offs, cursor, NRn);
    scatter_kernel<<<gE256, 256, 0, stream>>>(dstp, cursor, csr, En);

    // fused edge projection + attention logits + exp
    edge_kernel<<<gE64, 256, 0, stream>>>(ef, W_e, x_l, x_r, src, dstp, att, exb, En);

    // message + softmax-normalize + LayerNorm
    msg_ln_kernel<<<NRn, 128, 0, stream>>>(x_l, exb, csr, offs, src, bconv, ln_g, ln_b, msg);

    // output MLP: h = relu([msg|right] @ W1 + b1); out = h @ W2 + b2
    // split W1 along K (LDS budget): partial = msg @ W1[:128] -> x_r buf
    proj_kernel<<<gP_R, 256, 0, stream>>>(msg, W1, nullptr, nullptr, x_r, NRn, 0);
    // h = relu(right @ W1[128:] + b1 + partial) -> msg buf
    proj_kernel<<<gP_R, 256, 0, stream>>>(right, W1 + EMB * EMB, b1, x_r, msg, NRn, 1);
    // out = h @ W2 + b2
    proj_kernel<<<gP_R, 256, 0, stream>>>(msg, W2, b2, nullptr, (float*)d_out, NRn, 0);
}

// Round 2
// 1324.213 us; speedup vs baseline: 1.8062x; 1.8062x over previous
//
#include <hip/hip_runtime.h>
#include <math.h>

#define EMB 128

typedef __bf16 bf16x8 __attribute__((ext_vector_type(8)));
typedef float f32x4 __attribute__((ext_vector_type(4)));

// ---------------- helpers ----------------

__device__ __forceinline__ int incl_scan_256(int v, int* lds) {
    int tid = threadIdx.x;
    lds[tid] = v;
    __syncthreads();
    #pragma unroll
    for (int off = 1; off < 256; off <<= 1) {
        int t = (tid >= off) ? lds[tid - off] : 0;
        __syncthreads();
        lds[tid] += t;
        __syncthreads();
    }
    return lds[tid];
}

#define F4E(v, j) ((j) == 0 ? (v).x : ((j) == 1 ? (v).y : ((j) == 2 ? (v).z : (v).w)))

// ---------------- generic [M,128] @ [128,128] projection (fp32 VALU) ----------------
__global__ __launch_bounds__(256) void proj_kernel(
    const float* __restrict__ X, const float* __restrict__ W,
    const float* __restrict__ bias, const float* __restrict__ C,
    float* __restrict__ Y, int M, int relu)
{
    __shared__ float Wl[EMB * EMB];
    const int tid = threadIdx.x;
    for (int i = tid; i < EMB * EMB / 4; i += 256)
        ((float4*)Wl)[i] = ((const float4*)W)[i];
    __syncthreads();

    const int wave = tid >> 6, lane = tid & 63;
    const int base = blockIdx.x * 64 + wave * 16;

    float2 bv = make_float2(0.f, 0.f);
    if (bias) bv = *(const float2*)(bias + 2 * lane);

    for (int g = 0; g < 4; ++g) {
        const int r0 = base + g * 4;
        int rc[4];
        #pragma unroll
        for (int j = 0; j < 4; ++j) { int r = r0 + j; rc[j] = (r < M) ? r : (M - 1); }
        const float4* p0 = (const float4*)(X + (size_t)rc[0] * EMB);
        const float4* p1 = (const float4*)(X + (size_t)rc[1] * EMB);
        const float4* p2 = (const float4*)(X + (size_t)rc[2] * EMB);
        const float4* p3 = (const float4*)(X + (size_t)rc[3] * EMB);
        float2 a0 = bv, a1 = bv, a2 = bv, a3 = bv;
        #pragma unroll 4
        for (int k4 = 0; k4 < 32; ++k4) {
            float4 x0 = p0[k4], x1 = p1[k4], x2 = p2[k4], x3 = p3[k4];
            #pragma unroll
            for (int j = 0; j < 4; ++j) {
                float2 w = ((const float2*)(Wl + (k4 * 4 + j) * EMB))[lane];
                float f0 = F4E(x0, j), f1 = F4E(x1, j), f2 = F4E(x2, j), f3 = F4E(x3, j);
                a0.x += f0 * w.x; a0.y += f0 * w.y;
                a1.x += f1 * w.x; a1.y += f1 * w.y;
                a2.x += f2 * w.x; a2.y += f2 * w.y;
                a3.x += f3 * w.x; a3.y += f3 * w.y;
            }
        }
        #pragma unroll
        for (int j = 0; j < 4; ++j) {
            if (r0 + j < M) {
                float2 a = (j == 0) ? a0 : ((j == 1) ? a1 : ((j == 2) ? a2 : a3));
                if (C) {
                    float2 c = *(const float2*)(C + (size_t)(r0 + j) * EMB + 2 * lane);
                    a.x += c.x; a.y += c.y;
                }
                if (relu) { a.x = fmaxf(a.x, 0.f); a.y = fmaxf(a.y, 0.f); }
                *(float2*)(Y + (size_t)(r0 + j) * EMB + 2 * lane) = a;
            }
        }
    }
}

// ---------------- W_e fragment packer ----------------
// pack[((t*4+s)*64 + l)*8 + j] = bf16( W[(s*32 + (l>>4)*8 + j)*128 + t*16 + (l&15)] )
// so the edge kernel's B-frag read is: lane l reads 16 contiguous bytes at (t,s) chunk.
__global__ __launch_bounds__(256) void pack_we_kernel(const float* __restrict__ We,
                                                      __bf16* __restrict__ pack) {
    const int tid = threadIdx.x;
    for (int r = 0; r < 8; ++r) {
        int idx = tid + 256 * r;          // (t,s,l): l=idx&63, s=(idx>>6)&3, t=idx>>8
        int l = idx & 63, s = (idx >> 6) & 3, t = idx >> 8;
        #pragma unroll
        for (int j = 0; j < 8; ++j) {
            int k = s * 32 + ((l >> 4) * 8) + j;
            int n = t * 16 + (l & 15);
            pack[(size_t)idx * 8 + j] = (__bf16)We[k * EMB + n];
        }
    }
}

// ---------------- fused edge kernel (bf16 MFMA) ----------------
// per edge: e = ef @ W_e; z = leaky(x_l[src]+x_r[dst]+e, 0.2);
// logit[h] = sum_o z[h,o]*att[h,o]; ex[e,h] = exp(logit)
// block = 256 thr = 4 waves; 64 edges/block, 16 edges/wave; N=128 cols via 8 MFMA col-tiles.
__global__ __launch_bounds__(256) void edge_kernel(
    const float* __restrict__ EF, const __bf16* __restrict__ wpack,
    const float* __restrict__ xl, const float* __restrict__ xr,
    const int* __restrict__ src, const int* __restrict__ dst,
    const float* __restrict__ att, float* __restrict__ exb, int En)
{
    __shared__ __attribute__((aligned(16))) __bf16 Wl[EMB * EMB];  // 32 KB, frag-packed
    const int tid = threadIdx.x;
    {
        float4* d4 = (float4*)Wl;
        const float4* s4 = (const float4*)wpack;
        #pragma unroll
        for (int i = 0; i < 8; ++i) d4[tid + 256 * i] = s4[tid + 256 * i];
    }
    __syncthreads();

    const int l = tid & 63, wv = tid >> 6;
    const int q = l >> 4, c = l & 15;
    const int ebase = blockIdx.x * 64 + wv * 16;

    // ---- GEMM: acc[t] = EF[ebase..+16, :] @ W_e[:, t*16..+16] ----
    f32x4 acc[8];
    #pragma unroll
    for (int t = 0; t < 8; ++t) acc[t] = (f32x4){0.f, 0.f, 0.f, 0.f};

    int arow = ebase + c; if (arow >= En) arow = En - 1;
    const float* Ap = EF + (size_t)arow * EMB + q * 8;

    #pragma unroll
    for (int s = 0; s < 4; ++s) {
        float4 a0 = *(const float4*)(Ap + s * 32);
        float4 a1 = *(const float4*)(Ap + s * 32 + 4);
        bf16x8 af;
        af[0] = (__bf16)a0.x; af[1] = (__bf16)a0.y; af[2] = (__bf16)a0.z; af[3] = (__bf16)a0.w;
        af[4] = (__bf16)a1.x; af[5] = (__bf16)a1.y; af[6] = (__bf16)a1.z; af[7] = (__bf16)a1.w;
        #pragma unroll
        for (int t = 0; t < 8; ++t) {
            bf16x8 bf = *reinterpret_cast<const bf16x8*>(&Wl[((size_t)(t * 4 + s) * 64 + l) * 8]);
            acc[t] = __builtin_amdgcn_mfma_f32_16x16x32_bf16(af, bf, acc[t], 0, 0, 0);
        }
    }

    // ---- epilogue: leaky + att-dot + head-reduce + exp ----
    // C layout: col = t*16 + c, row(edge) = ebase + q*4 + reg
    float attv[8];
    #pragma unroll
    for (int t = 0; t < 8; ++t) attv[t] = att[t * 16 + c];

    float v[4][4];  // [reg i][head h]
    const int e0 = ebase + q * 4;
    #pragma unroll
    for (int i = 0; i < 4; ++i) {
        int ei = e0 + i; if (ei >= En) ei = En - 1;
        const int se = src[ei], de = dst[ei];
        const float* xls = xl + (size_t)se * EMB;
        const float* xrs = xr + (size_t)de * EMB;
        float ph[4] = {0.f, 0.f, 0.f, 0.f};
        #pragma unroll
        for (int t = 0; t < 8; ++t) {
            int col = t * 16 + c;
            float z = acc[t][i] + xls[col] + xrs[col];
            z = (z > 0.f) ? z : 0.2f * z;
            ph[t >> 1] += z * attv[t];
        }
        #pragma unroll
        for (int h = 0; h < 4; ++h) v[i][h] = ph[h];
    }

    // butterfly across the 16 lanes of this row-group (all share q)
    #pragma unroll
    for (int m = 1; m < 16; m <<= 1) {
        #pragma unroll
        for (int i = 0; i < 4; ++i)
            #pragma unroll
            for (int h = 0; h < 4; ++h)
                v[i][h] += __shfl_xor(v[i][h], m);
    }

    // lane c (0..15) writes (edge reg = c>>2, head = c&3)
    const int si = c >> 2, sh = c & 3;
    float val = v[0][0];
    #pragma unroll
    for (int i = 0; i < 4; ++i)
        #pragma unroll
        for (int h = 0; h < 4; ++h)
            if (si == i && sh == h) val = v[i][h];
    const int ew = e0 + si;
    if (ew < En) exb[(size_t)ew * 4 + sh] = expf(val);
}

// ---------------- CSR build ----------------
__global__ void hist_kernel(const int* __restrict__ dst, int* __restrict__ counts, int En) {
    int i = blockIdx.x * 256 + threadIdx.x;
    if (i < En) atomicAdd(&counts[dst[i]], 1);
}

__global__ void scan1_kernel(const int* __restrict__ counts, int* __restrict__ bsum, int N) {
    __shared__ int red[4];
    int i = blockIdx.x * 256 + threadIdx.x;
    int v = (i < N) ? counts[i] : 0;
    #pragma unroll
    for (int m = 1; m < 64; m <<= 1) v += __shfl_xor(v, m);
    if ((threadIdx.x & 63) == 0) red[threadIdx.x >> 6] = v;
    __syncthreads();
    if (threadIdx.x == 0) bsum[blockIdx.x] = red[0] + red[1] + red[2] + red[3];
}

__global__ void scan2_kernel(int* __restrict__ bsum, int* __restrict__ boff, int nb,
                             int* __restrict__ offs, int NRtot, int Etot) {
    __shared__ int lds[256];
    int tid = threadIdx.x;
    int v = (tid < nb) ? bsum[tid] : 0;
    int incl = incl_scan_256(v, lds);
    if (tid < nb) boff[tid] = incl - v;
    if (tid == 0) offs[NRtot] = Etot;
}

__global__ void scan3_kernel(const int* __restrict__ counts, const int* __restrict__ boff,
                             int* __restrict__ offs, int* __restrict__ cursor, int N) {
    __shared__ int lds[256];
    int tid = threadIdx.x;
    int i = blockIdx.x * 256 + tid;
    int v = (i < N) ? counts[i] : 0;
    int incl = incl_scan_256(v, lds);
    int excl = incl - v + boff[blockIdx.x];
    if (i < N) { offs[i] = excl; cursor[i] = excl; }
}

__global__ void scatter_kernel(const int* __restrict__ dst, int* __restrict__ cursor,
                               int* __restrict__ csr, int En) {
    int i = blockIdx.x * 256 + threadIdx.x;
    if (i < En) { int p = atomicAdd(&cursor[dst[i]], 1); csr[p] = i; }
}

// ---------------- message accumulation + softmax-normalize + LayerNorm ----------------
__global__ __launch_bounds__(128) void msg_ln_kernel(
    const float* __restrict__ xl, const float* __restrict__ exb,
    const int* __restrict__ csr, const int* __restrict__ offs,
    const int* __restrict__ src, const float* __restrict__ bconv,
    const float* __restrict__ ln_g, const float* __restrict__ ln_b,
    float* __restrict__ msg)
{
    const int d = blockIdx.x;
    const int tid = threadIdx.x;
    const int h = tid >> 5;
    const int beg = offs[d], end = offs[d + 1];
    float acc = 0.f, den = 0.f;
    for (int i = beg; i < end; ++i) {
        int e = csr[i];
        float exv = exb[(size_t)e * 4 + h];
        int s = src[e];
        acc += exv * xl[(size_t)s * EMB + tid];
        den += exv;
    }
    float m = acc / (den + 1e-16f) + bconv[tid];

    __shared__ float red[2];
    float s1 = m;
    #pragma unroll
    for (int mk = 1; mk < 64; mk <<= 1) s1 += __shfl_xor(s1, mk);
    if ((tid & 63) == 0) red[tid >> 6] = s1;
    __syncthreads();
    float mu = (red[0] + red[1]) * (1.f / EMB);
    __syncthreads();
    float c = m - mu;
    float s2 = c * c;
    #pragma unroll
    for (int mk = 1; mk < 64; mk <<= 1) s2 += __shfl_xor(s2, mk);
    if ((tid & 63) == 0) red[tid >> 6] = s2;
    __syncthreads();
    float var = (red[0] + red[1]) * (1.f / EMB);
    float y = c * (1.f / sqrtf(var + 1e-5f)) * ln_g[tid] + ln_b[tid];
    msg[(size_t)d * EMB + tid] = y;
}

// ---------------- launch ----------------
extern "C" void kernel_launch(void* const* d_in, const int* in_sizes, int n_in,
                              void* d_out, int out_size, void* d_ws, size_t ws_size,
                              hipStream_t stream) {
    const float* left  = (const float*)d_in[0];
    const int*   eidx  = (const int*)d_in[1];
    const float* ef    = (const float*)d_in[2];
    const float* right = (const float*)d_in[3];
    const float* W_l   = (const float*)d_in[4];
    const float* b_l   = (const float*)d_in[5];
    const float* W_r   = (const float*)d_in[6];
    const float* b_r   = (const float*)d_in[7];
    const float* W_e   = (const float*)d_in[8];
    const float* att   = (const float*)d_in[9];
    const float* bconv = (const float*)d_in[10];
    const float* ln_g  = (const float*)d_in[11];
    const float* ln_b  = (const float*)d_in[12];
    const float* W1    = (const float*)d_in[13];
    const float* b1    = (const float*)d_in[14];
    const float* W2    = (const float*)d_in[15];
    const float* b2    = (const float*)d_in[16];

    const int NLn = in_sizes[0] / EMB;
    const int En  = in_sizes[1] / 2;
    const int NRn = in_sizes[3] / EMB;
    const int* src  = eidx;
    const int* dstp = eidx + En;

    // workspace carve (wpack first, 16-B aligned at base)
    __bf16* wpack = (__bf16*)d_ws;
    float* fws = (float*)d_ws + (EMB * EMB / 2);  // 32 KB of bf16 = 8192 floats... (128*128 bf16 = 32768B = 8192 floats/4) -> use element math below
    // EMB*EMB bf16 elements = 16384 * 2 B = 32768 B = 8192 floats
    fws = (float*)d_ws + 8192;
    size_t off = 0;
    float* x_l = fws + off; off += (size_t)NLn * EMB;
    float* x_r = fws + off; off += (size_t)NRn * EMB;   // later reused as MLP partial buf
    float* exb = fws + off; off += (size_t)En * 4;
    float* msg = fws + off; off += (size_t)NRn * EMB;   // later reused as h buf
    int* counts = (int*)(fws + off);
    int* offs   = counts + NRn;
    int* cursor = offs + NRn + 1;
    int* bsum   = cursor + NRn;
    int* boff   = bsum + 256;
    int* csr    = boff + 256;

    const int nb = (NRn + 255) / 256;
    const int gP_L = (NLn + 63) / 64;
    const int gP_R = (NRn + 63) / 64;
    const int gE64 = (En + 63) / 64;
    const int gE256 = (En + 255) / 256;

    hipMemsetAsync(counts, 0, (size_t)NRn * sizeof(int), stream);

    // W_e fragment pack (one tiny block)
    pack_we_kernel<<<1, 256, 0, stream>>>(W_e, wpack);

    // node projections
    proj_kernel<<<gP_L, 256, 0, stream>>>(left,  W_l, b_l, nullptr, x_l, NLn, 0);
    proj_kernel<<<gP_R, 256, 0, stream>>>(right, W_r, b_r, nullptr, x_r, NRn, 0);

    // CSR by dst
    hist_kernel<<<gE256, 256, 0, stream>>>(dstp, counts, En);
    scan1_kernel<<<nb, 256, 0, stream>>>(counts, bsum, NRn);
    scan2_kernel<<<1, 256, 0, stream>>>(bsum, boff, nb, offs, NRn, En);
    scan3_kernel<<<nb, 256, 0, stream>>>(counts, boff, offs, cursor, NRn);
    scatter_kernel<<<gE256, 256, 0, stream>>>(dstp, cursor, csr, En);

    // fused edge projection + attention logits + exp (bf16 MFMA)
    edge_kernel<<<gE64, 256, 0, stream>>>(ef, wpack, x_l, x_r, src, dstp, att, exb, En);

    // message + softmax-normalize + LayerNorm
    msg_ln_kernel<<<NRn, 128, 0, stream>>>(x_l, exb, csr, offs, src, bconv, ln_g, ln_b, msg);

    // output MLP: h = relu([msg|right] @ W1 + b1); out = h @ W2 + b2
    proj_kernel<<<gP_R, 256, 0, stream>>>(msg, W1, nullptr, nullptr, x_r, NRn, 0);
    proj_kernel<<<gP_R, 256, 0, stream>>>(right, W1 + EMB * EMB, b1, x_r, msg, NRn, 1);
    proj_kernel<<<gP_R, 256, 0, stream>>>(msg, W2, b2, nullptr, (float*)d_out, NRn, 0);
}

// Round 3
// 978.194 us; speedup vs baseline: 2.4452x; 1.3537x over previous
//
#include <hip/hip_runtime.h>
#include <math.h>

#define EMB 128

typedef __bf16 bf16x8 __attribute__((ext_vector_type(8)));
typedef float f32x4 __attribute__((ext_vector_type(4)));

// ---------------- helpers ----------------

__device__ __forceinline__ int incl_scan_256(int v, int* lds) {
    int tid = threadIdx.x;
    lds[tid] = v;
    __syncthreads();
    #pragma unroll
    for (int off = 1; off < 256; off <<= 1) {
        int t = (tid >= off) ? lds[tid - off] : 0;
        __syncthreads();
        lds[tid] += t;
        __syncthreads();
    }
    return lds[tid];
}

// ---------------- generic W fragment packer ----------------
// W is [K, 128] (K = 128 or 256). B-frag order for mfma_f32_16x16x32_bf16:
// pack[((t*(K/32)+s)*64 + l)*8 + j] = bf16( W[(s*32 + (l>>4)*8 + j)*128 + t*16 + (l&15)] )
__global__ void pack_w_kernel(const float* __restrict__ W, __bf16* __restrict__ pack, int K) {
    const int ksteps = K >> 5;
    const int nchunk = 8 * ksteps * 64;
    for (int idx = blockIdx.x * 256 + threadIdx.x; idx < nchunk; idx += 256 * gridDim.x) {
        int l = idx & 63;
        int s = (idx >> 6) % ksteps;
        int t = (idx >> 6) / ksteps;
        #pragma unroll
        for (int j = 0; j < 8; ++j) {
            int k = s * 32 + ((l >> 4) * 8) + j;
            int n = t * 16 + (l & 15);
            pack[(size_t)idx * 8 + j] = (__bf16)W[(size_t)k * EMB + n];
        }
    }
}

// ---------------- MFMA projection: Y = act(X @ W + bias) ----------------
// K = KSTEPS*32. For KSTEPS==8, A rows are the concat [X0[r,:128] | X1[r,:128]].
// block = 256 (4 waves); each wave one M=16 row tile, 8 col tiles (N=128).
template<int KSTEPS>
__global__ __launch_bounds__(256) void proj_mfma(
    const float* __restrict__ X0, const float* __restrict__ X1,
    const __bf16* __restrict__ wpack, const float* __restrict__ bias,
    float* __restrict__ Y, int M, int relu)
{
    __shared__ __attribute__((aligned(16))) __bf16 Wl[KSTEPS * 8 * 64 * 8];
    const int tid = threadIdx.x;
    #pragma unroll
    for (int i = tid; i < KSTEPS * 512; i += 256)
        ((float4*)Wl)[i] = ((const float4*)wpack)[i];
    __syncthreads();

    const int l = tid & 63, wv = tid >> 6;
    const int q = l >> 4, c = l & 15;
    const int rbase = blockIdx.x * 64 + wv * 16;

    int arow = rbase + c; if (arow >= M) arow = M - 1;
    const float* Ap0 = X0 + (size_t)arow * EMB + q * 8;
    const float* Ap1 = (KSTEPS == 8) ? (X1 + (size_t)arow * EMB + q * 8) : Ap0;

    f32x4 acc[8];
    #pragma unroll
    for (int t = 0; t < 8; ++t) acc[t] = (f32x4){0.f, 0.f, 0.f, 0.f};

    #pragma unroll
    for (int s = 0; s < KSTEPS; ++s) {
        const float* bp = (s < 4) ? Ap0 : Ap1;
        const int ss = (s < 4) ? s : s - 4;
        float4 a0 = *(const float4*)(bp + ss * 32);
        float4 a1 = *(const float4*)(bp + ss * 32 + 4);
        bf16x8 af;
        af[0] = (__bf16)a0.x; af[1] = (__bf16)a0.y; af[2] = (__bf16)a0.z; af[3] = (__bf16)a0.w;
        af[4] = (__bf16)a1.x; af[5] = (__bf16)a1.y; af[6] = (__bf16)a1.z; af[7] = (__bf16)a1.w;
        #pragma unroll
        for (int t = 0; t < 8; ++t) {
            bf16x8 bf = *reinterpret_cast<const bf16x8*>(&Wl[((size_t)(t * KSTEPS + s) * 64 + l) * 8]);
            acc[t] = __builtin_amdgcn_mfma_f32_16x16x32_bf16(af, bf, acc[t], 0, 0, 0);
        }
    }

    // epilogue: C layout col = t*16+c, row = rbase + q*4 + reg
    const int r0 = rbase + q * 4;
    #pragma unroll
    for (int t = 0; t < 8; ++t) {
        const int col = t * 16 + c;
        const float b = bias ? bias[col] : 0.f;
        #pragma unroll
        for (int i = 0; i < 4; ++i) {
            const int r = r0 + i;
            if (r < M) {
                float v = acc[t][i] + b;
                if (relu) v = fmaxf(v, 0.f);
                Y[(size_t)r * EMB + col] = v;
            }
        }
    }
}

// ---------------- fused edge kernel (bf16 MFMA) ----------------
__global__ __launch_bounds__(256) void edge_kernel(
    const float* __restrict__ EF, const __bf16* __restrict__ wpack,
    const float* __restrict__ xl, const float* __restrict__ xr,
    const int* __restrict__ src, const int* __restrict__ dst,
    const float* __restrict__ att, float* __restrict__ exb, int En)
{
    __shared__ __attribute__((aligned(16))) __bf16 Wl[EMB * EMB];  // 32 KB, frag-packed
    const int tid = threadIdx.x;
    {
        float4* d4 = (float4*)Wl;
        const float4* s4 = (const float4*)wpack;
        #pragma unroll
        for (int i = 0; i < 8; ++i) d4[tid + 256 * i] = s4[tid + 256 * i];
    }
    __syncthreads();

    const int l = tid & 63, wv = tid >> 6;
    const int q = l >> 4, c = l & 15;
    const int ebase = blockIdx.x * 64 + wv * 16;

    f32x4 acc[8];
    #pragma unroll
    for (int t = 0; t < 8; ++t) acc[t] = (f32x4){0.f, 0.f, 0.f, 0.f};

    int arow = ebase + c; if (arow >= En) arow = En - 1;
    const float* Ap = EF + (size_t)arow * EMB + q * 8;

    #pragma unroll
    for (int s = 0; s < 4; ++s) {
        float4 a0 = *(const float4*)(Ap + s * 32);
        float4 a1 = *(const float4*)(Ap + s * 32 + 4);
        bf16x8 af;
        af[0] = (__bf16)a0.x; af[1] = (__bf16)a0.y; af[2] = (__bf16)a0.z; af[3] = (__bf16)a0.w;
        af[4] = (__bf16)a1.x; af[5] = (__bf16)a1.y; af[6] = (__bf16)a1.z; af[7] = (__bf16)a1.w;
        #pragma unroll
        for (int t = 0; t < 8; ++t) {
            bf16x8 bf = *reinterpret_cast<const bf16x8*>(&Wl[((size_t)(t * 4 + s) * 64 + l) * 8]);
            acc[t] = __builtin_amdgcn_mfma_f32_16x16x32_bf16(af, bf, acc[t], 0, 0, 0);
        }
    }

    // epilogue: leaky + att-dot + head-reduce + exp
    float attv[8];
    #pragma unroll
    for (int t = 0; t < 8; ++t) attv[t] = att[t * 16 + c];

    float v[4][4];  // [reg i][head h]
    const int e0 = ebase + q * 4;
    #pragma unroll
    for (int i = 0; i < 4; ++i) {
        int ei = e0 + i; if (ei >= En) ei = En - 1;
        const int se = src[ei], de = dst[ei];
        const float* xls = xl + (size_t)se * EMB;
        const float* xrs = xr + (size_t)de * EMB;
        float ph[4] = {0.f, 0.f, 0.f, 0.f};
        #pragma unroll
        for (int t = 0; t < 8; ++t) {
            int col = t * 16 + c;
            float z = acc[t][i] + xls[col] + xrs[col];
            z = (z > 0.f) ? z : 0.2f * z;
            ph[t >> 1] += z * attv[t];
        }
        #pragma unroll
        for (int h = 0; h < 4; ++h) v[i][h] = ph[h];
    }

    #pragma unroll
    for (int m = 1; m < 16; m <<= 1) {
        #pragma unroll
        for (int i = 0; i < 4; ++i)
            #pragma unroll
            for (int h = 0; h < 4; ++h)
                v[i][h] += __shfl_xor(v[i][h], m);
    }

    const int si = c >> 2, sh = c & 3;
    float val = v[0][0];
    #pragma unroll
    for (int i = 0; i < 4; ++i)
        #pragma unroll
        for (int h = 0; h < 4; ++h)
            if (si == i && sh == h) val = v[i][h];
    const int ew = e0 + si;
    if (ew < En) exb[(size_t)ew * 4 + sh] = expf(val);
}

// ---------------- CSR build ----------------
__global__ void hist_kernel(const int* __restrict__ dst, int* __restrict__ counts, int En) {
    int i = blockIdx.x * 256 + threadIdx.x;
    if (i < En) atomicAdd(&counts[dst[i]], 1);
}

__global__ void scan1_kernel(const int* __restrict__ counts, int* __restrict__ bsum, int N) {
    __shared__ int red[4];
    int i = blockIdx.x * 256 + threadIdx.x;
    int v = (i < N) ? counts[i] : 0;
    #pragma unroll
    for (int m = 1; m < 64; m <<= 1) v += __shfl_xor(v, m);
    if ((threadIdx.x & 63) == 0) red[threadIdx.x >> 6] = v;
    __syncthreads();
    if (threadIdx.x == 0) bsum[blockIdx.x] = red[0] + red[1] + red[2] + red[3];
}

__global__ void scan2_kernel(int* __restrict__ bsum, int* __restrict__ boff, int nb,
                             int* __restrict__ offs, int NRtot, int Etot) {
    __shared__ int lds[256];
    int tid = threadIdx.x;
    int v = (tid < nb) ? bsum[tid] : 0;
    int incl = incl_scan_256(v, lds);
    if (tid < nb) boff[tid] = incl - v;
    if (tid == 0) offs[NRtot] = Etot;
}

__global__ void scan3_kernel(const int* __restrict__ counts, const int* __restrict__ boff,
                             int* __restrict__ offs, int* __restrict__ cursor, int N) {
    __shared__ int lds[256];
    int tid = threadIdx.x;
    int i = blockIdx.x * 256 + tid;
    int v = (i < N) ? counts[i] : 0;
    int incl = incl_scan_256(v, lds);
    int excl = incl - v + boff[blockIdx.x];
    if (i < N) { offs[i] = excl; cursor[i] = excl; }
}

__global__ void scatter_kernel(const int* __restrict__ dst, int* __restrict__ cursor,
                               int* __restrict__ csr, int En) {
    int i = blockIdx.x * 256 + threadIdx.x;
    if (i < En) { int p = atomicAdd(&cursor[dst[i]], 1); csr[p] = i; }
}

// ---------------- message accumulation + softmax-normalize + LayerNorm ----------------
__global__ __launch_bounds__(128) void msg_ln_kernel(
    const float* __restrict__ xl, const float* __restrict__ exb,
    const int* __restrict__ csr, const int* __restrict__ offs,
    const int* __restrict__ src, const float* __restrict__ bconv,
    const float* __restrict__ ln_g, const float* __restrict__ ln_b,
    float* __restrict__ msg)
{
    const int d = blockIdx.x;
    const int tid = threadIdx.x;
    const int h = tid >> 5;
    const int beg = offs[d], end = offs[d + 1];
    float acc = 0.f, den = 0.f;
    for (int i = beg; i < end; ++i) {
        int e = csr[i];
        float exv = exb[(size_t)e * 4 + h];
        int s = src[e];
        acc += exv * xl[(size_t)s * EMB + tid];
        den += exv;
    }
    float m = acc / (den + 1e-16f) + bconv[tid];

    __shared__ float red[2];
    float s1 = m;
    #pragma unroll
    for (int mk = 1; mk < 64; mk <<= 1) s1 += __shfl_xor(s1, mk);
    if ((tid & 63) == 0) red[tid >> 6] = s1;
    __syncthreads();
    float mu = (red[0] + red[1]) * (1.f / EMB);
    __syncthreads();
    float c = m - mu;
    float s2 = c * c;
    #pragma unroll
    for (int mk = 1; mk < 64; mk <<= 1) s2 += __shfl_xor(s2, mk);
    if ((tid & 63) == 0) red[tid >> 6] = s2;
    __syncthreads();
    float var = (red[0] + red[1]) * (1.f / EMB);
    float y = c * (1.f / sqrtf(var + 1e-5f)) * ln_g[tid] + ln_b[tid];
    msg[(size_t)d * EMB + tid] = y;
}

// ---------------- launch ----------------
extern "C" void kernel_launch(void* const* d_in, const int* in_sizes, int n_in,
                              void* d_out, int out_size, void* d_ws, size_t ws_size,
                              hipStream_t stream) {
    const float* left  = (const float*)d_in[0];
    const int*   eidx  = (const int*)d_in[1];
    const float* ef    = (const float*)d_in[2];
    const float* right = (const float*)d_in[3];
    const float* W_l   = (const float*)d_in[4];
    const float* b_l   = (const float*)d_in[5];
    const float* W_r   = (const float*)d_in[6];
    const float* b_r   = (const float*)d_in[7];
    const float* W_e   = (const float*)d_in[8];
    const float* att   = (const float*)d_in[9];
    const float* bconv = (const float*)d_in[10];
    const float* ln_g  = (const float*)d_in[11];
    const float* ln_b  = (const float*)d_in[12];
    const float* W1    = (const float*)d_in[13];
    const float* b1    = (const float*)d_in[14];
    const float* W2    = (const float*)d_in[15];
    const float* b2    = (const float*)d_in[16];

    const int NLn = in_sizes[0] / EMB;
    const int En  = in_sizes[1] / 2;
    const int NRn = in_sizes[3] / EMB;
    const int* src  = eidx;
    const int* dstp = eidx + En;

    // workspace carve: bf16 packs first (16-B aligned at base)
    // sizes in bf16 elements: we 16384, wl 16384, wr 16384, w1 32768, w2 16384 = 98304
    __bf16* we_pack = (__bf16*)d_ws;
    __bf16* wl_pack = we_pack + 16384;
    __bf16* wr_pack = wl_pack + 16384;
    __bf16* w1_pack = wr_pack + 16384;
    __bf16* w2_pack = w1_pack + 32768;
    float* fws = (float*)d_ws + 49152;  // 98304 bf16 = 196608 B = 49152 floats
    size_t off = 0;
    float* x_l = fws + off; off += (size_t)NLn * EMB;
    float* x_r = fws + off; off += (size_t)NRn * EMB;   // reused as h buf in MLP
    float* exb = fws + off; off += (size_t)En * 4;
    float* msg = fws + off; off += (size_t)NRn * EMB;
    int* counts = (int*)(fws + off);
    int* offs   = counts + NRn;
    int* cursor = offs + NRn + 1;
    int* bsum   = cursor + NRn;
    int* boff   = bsum + 256;
    int* csr    = boff + 256;

    const int nb = (NRn + 255) / 256;
    const int gP_L = (NLn + 63) / 64;
    const int gP_R = (NRn + 63) / 64;
    const int gE64 = (En + 63) / 64;
    const int gE256 = (En + 255) / 256;

    hipMemsetAsync(counts, 0, (size_t)NRn * sizeof(int), stream);

    // weight fragment packs
    pack_w_kernel<<<8, 256, 0, stream>>>(W_e, we_pack, 128);
    pack_w_kernel<<<8, 256, 0, stream>>>(W_l, wl_pack, 128);
    pack_w_kernel<<<8, 256, 0, stream>>>(W_r, wr_pack, 128);
    pack_w_kernel<<<16, 256, 0, stream>>>(W1, w1_pack, 256);
    pack_w_kernel<<<8, 256, 0, stream>>>(W2, w2_pack, 128);

    // node projections (MFMA)
    proj_mfma<4><<<gP_L, 256, 0, stream>>>(left,  nullptr, wl_pack, b_l, x_l, NLn, 0);
    proj_mfma<4><<<gP_R, 256, 0, stream>>>(right, nullptr, wr_pack, b_r, x_r, NRn, 0);

    // CSR by dst
    hist_kernel<<<gE256, 256, 0, stream>>>(dstp, counts, En);
    scan1_kernel<<<nb, 256, 0, stream>>>(counts, bsum, NRn);
    scan2_kernel<<<1, 256, 0, stream>>>(bsum, boff, nb, offs, NRn, En);
    scan3_kernel<<<nb, 256, 0, stream>>>(counts, boff, offs, cursor, NRn);
    scatter_kernel<<<gE256, 256, 0, stream>>>(dstp, cursor, csr, En);

    // fused edge projection + attention logits + exp (bf16 MFMA)
    edge_kernel<<<gE64, 256, 0, stream>>>(ef, we_pack, x_l, x_r, src, dstp, att, exb, En);

    // message + softmax-normalize + LayerNorm
    msg_ln_kernel<<<NRn, 128, 0, stream>>>(x_l, exb, csr, offs, src, bconv, ln_g, ln_b, msg);

    // output MLP: h = relu([msg|right] @ W1 + b1) in ONE kernel (K=256), then out = h @ W2 + b2
    proj_mfma<8><<<gP_R, 256, 0, stream>>>(msg, right, w1_pack, b1, x_r, NRn, 1);
    proj_mfma<4><<<gP_R, 256, 0, stream>>>(x_r, nullptr, w2_pack, b2, (float*)d_out, NRn, 0);
}